// Round 2
// baseline (433.099 us; speedup 1.0000x reference)
//
#include <hip/hip_runtime.h>
#include <hip/hip_bf16.h>

#define NUM_CLASSES 6
#define NUM_SUBJECTS 16
#define NUM_PAIRS (NUM_CLASSES * NUM_SUBJECTS)   // 96
#define MARGIN 1.0f
#define EPS 1e-6f
#define INF_I 0x7fffffff

// ---------------- ws layout (bytes) ----------------
// [0)      int   min1[96]
// [384)    int   min2[96]
// [768)    int   cntPos[96]
// [1152)   int   cntSbj[16]
// [1216)   u64   best[96]        packed (sortable_f32(d2)<<32)|idx
// [1984)   float a2[96]
// [2368)   int   cursor[16]
// [2432)   f32   anchors[96*256] (float4-aligned)
// [395648) int   order[B]        samples grouped by subject
// total ~0.92 MB

__device__ __forceinline__ float wredsum(float v) {
#pragma unroll
    for (int m = 32; m >= 1; m >>= 1) v += __shfl_xor(v, m, 64);
    return v;
}

__device__ __forceinline__ unsigned int fkey(float f) {
    unsigned int b = __float_as_uint(f);
    return (b & 0x80000000u) ? ~b : (b | 0x80000000u);
}

__global__ void k_init(int* min1, int* min2, int* cntPos, int* cntSbj,
                       unsigned long long* best, float* a2, int* cursor) {
    int t = threadIdx.x;
    if (t < NUM_PAIRS) {
        min1[t] = INF_I;
        min2[t] = INF_I;
        cntPos[t] = 0;
        best[t] = ~0ull;
        a2[t] = 0.f;
    }
    if (t < NUM_SUBJECTS) cursor[t] = 0;
    if (t >= 64 && t - 64 < NUM_SUBJECTS) cntSbj[t - 64] = 0;
}

// Fused: first-two-positive mining + counts, single pass.
// Lock-free two-min: o = atomicMin(min1, i); atomicMin(min2, max(o, i)).
__global__ void k_stats(const int* __restrict__ labels, const int* __restrict__ sbj,
                        int* min1, int* min2, int* cntPos, int* cntSbj, int B) {
    __shared__ int l1[NUM_PAIRS], l2[NUM_PAIRS], lcp[NUM_PAIRS], lcs[NUM_SUBJECTS];
    for (int t = threadIdx.x; t < NUM_PAIRS; t += blockDim.x) { l1[t] = INF_I; l2[t] = INF_I; lcp[t] = 0; }
    if (threadIdx.x < NUM_SUBJECTS) lcs[threadIdx.x] = 0;
    __syncthreads();
    int i = blockIdx.x * blockDim.x + threadIdx.x;
    if (i < B) {
        int s = sbj[i], c = labels[i];
        int p = s * NUM_CLASSES + c;
        int o = atomicMin(&l1[p], i);
        atomicMin(&l2[p], max(o, i));   // max(INF,i)=INF -> no-op on first insert
        atomicAdd(&lcp[p], 1);
        atomicAdd(&lcs[s], 1);
    }
    __syncthreads();
    for (int t = threadIdx.x; t < NUM_PAIRS; t += blockDim.x) {
        int m1 = l1[t];
        if (m1 != INF_I) {
            int o = atomicMin(&min1[t], m1);
            atomicMin(&min2[t], max(o, m1));
            if (l2[t] != INF_I) atomicMin(&min2[t], l2[t]);
            atomicAdd(&cntPos[t], lcp[t]);
        }
    }
    if (threadIdx.x < NUM_SUBJECTS && lcs[threadIdx.x]) atomicAdd(&cntSbj[threadIdx.x], lcs[threadIdx.x]);
}

// Counting-sort by subject (order within subject is arbitrary; mining is
// order-invariant since the packed min key includes the original index).
__global__ void k_scatter(const int* __restrict__ sbj, const int* __restrict__ cntSbj,
                          int* cursor, int* order, int B) {
    __shared__ int lhist[NUM_SUBJECTS];
    __shared__ int gstart[NUM_SUBJECTS];
    __shared__ int pbase[NUM_SUBJECTS];
    if (threadIdx.x < NUM_SUBJECTS) lhist[threadIdx.x] = 0;
    __syncthreads();
    int i = blockIdx.x * blockDim.x + threadIdx.x;
    int s = 0, lrank = 0;
    bool act = i < B;
    if (act) { s = sbj[i]; lrank = atomicAdd(&lhist[s], 1); }
    __syncthreads();
    if (threadIdx.x == 0) {
        int acc = 0;
#pragma unroll
        for (int t = 0; t < NUM_SUBJECTS; ++t) { pbase[t] = acc; acc += cntSbj[t]; }
    }
    if (threadIdx.x < NUM_SUBJECTS)
        gstart[threadIdx.x] = atomicAdd(&cursor[threadIdx.x], lhist[threadIdx.x]);
    __syncthreads();
    if (act) order[pbase[s] + gstart[s] + lrank] = i;
}

__global__ void k_gather(const float4* __restrict__ emb4, const int* __restrict__ min1,
                         float4* anchors4, float* a2, int B) {
    int p = blockIdx.x;          // 96 blocks
    int lane = threadIdx.x;      // 64 threads
    int idx = min1[p];
    if (idx < 0 || idx >= B) idx = 0;
    float4 v = emb4[(size_t)idx * 64 + lane];
    anchors4[(size_t)p * 64 + lane] = v;
    float t = v.x * v.x + v.y * v.y + v.z * v.z + v.w * v.w;
    t = wredsum(t);
    if (lane == 0) a2[p] = t;
}

#define BPS 32   // blocks per subject; grid = 16*BPS = 512

__global__ __launch_bounds__(1024) void k_mine(const float4* __restrict__ emb4,
                                               const int* __restrict__ labels,
                                               const int* __restrict__ order,
                                               const int* __restrict__ cntSbj,
                                               const float4* __restrict__ anchors4,
                                               const float* __restrict__ a2,
                                               unsigned long long* gbest, int B) {
    __shared__ float4 ancLds[NUM_CLASSES][4][17];   // padded: q-stride 17 f4 -> 4 distinct banks
    __shared__ float a2l[NUM_CLASSES];
    __shared__ unsigned long long lbest[NUM_CLASSES];

    const int s = blockIdx.x & (NUM_SUBJECTS - 1);
    const int j = blockIdx.x >> 4;                  // 0..BPS-1

    int off = 0, cnt = 0;
#pragma unroll
    for (int t = 0; t < NUM_SUBJECTS; ++t) {
        int c = cntSbj[t];
        if (t < s) off += c;
        if (t == s) cnt = c;
    }

    int t = threadIdx.x;
    if (t < NUM_CLASSES * 64) {
        int c = t >> 6, l = t & 63;
        ancLds[c][l >> 4][l & 15] = anchors4[(size_t)(s * NUM_CLASSES + c) * 64 + l];
    }
    if (t < NUM_CLASSES) { a2l[t] = a2[s * NUM_CLASSES + t]; lbest[t] = ~0ull; }
    __syncthreads();
    if (cnt <= 0) return;

    const int lane = threadIdx.x & 63;
    const int g = lane & 15;        // sample-in-chunk
    const int q = lane >> 4;        // dim-quarter
    const int wv = (int)(threadIdx.x >> 6);
    const int waveGlob = j * 16 + wv;               // 0..16*BPS-1
    const int nwv = 16 * BPS;
    const int nchunk = (cnt + 15) >> 4;

    unsigned long long rmin0 = ~0ull, rmin1 = ~0ull, rmin2 = ~0ull,
                       rmin3 = ~0ull, rmin4 = ~0ull, rmin5 = ~0ull;

    for (int ch = waveGlob; ch < nchunk; ch += nwv) {
        int start = ch << 4;
        int rem = cnt - start;
        int gi = start + ((g < rem) ? g : (rem - 1));
        bool valid = g < rem;
        int id = order[off + gi];
        int lbl = labels[id];
        const float4* row = emb4 + (size_t)id * 64 + q * 16;
        float e2 = 0.f, d0 = 0.f, d1 = 0.f, d2s = 0.f, d3 = 0.f, d4 = 0.f, d5 = 0.f;
#pragma unroll
        for (int k = 0; k < 16; ++k) {
            float4 v = row[k];
            e2 = fmaf(v.x, v.x, fmaf(v.y, v.y, fmaf(v.z, v.z, fmaf(v.w, v.w, e2))));
            float4 a;
            a = ancLds[0][q][k]; d0  = fmaf(a.x, v.x, fmaf(a.y, v.y, fmaf(a.z, v.z, fmaf(a.w, v.w, d0))));
            a = ancLds[1][q][k]; d1  = fmaf(a.x, v.x, fmaf(a.y, v.y, fmaf(a.z, v.z, fmaf(a.w, v.w, d1))));
            a = ancLds[2][q][k]; d2s = fmaf(a.x, v.x, fmaf(a.y, v.y, fmaf(a.z, v.z, fmaf(a.w, v.w, d2s))));
            a = ancLds[3][q][k]; d3  = fmaf(a.x, v.x, fmaf(a.y, v.y, fmaf(a.z, v.z, fmaf(a.w, v.w, d3))));
            a = ancLds[4][q][k]; d4  = fmaf(a.x, v.x, fmaf(a.y, v.y, fmaf(a.z, v.z, fmaf(a.w, v.w, d4))));
            a = ancLds[5][q][k]; d5  = fmaf(a.x, v.x, fmaf(a.y, v.y, fmaf(a.z, v.z, fmaf(a.w, v.w, d5))));
        }
        // reduce the 4 dim-quarters (partners lane^16, lane^32): 2 shuffles each
        e2  += __shfl_xor(e2, 16, 64);  e2  += __shfl_xor(e2, 32, 64);
        d0  += __shfl_xor(d0, 16, 64);  d0  += __shfl_xor(d0, 32, 64);
        d1  += __shfl_xor(d1, 16, 64);  d1  += __shfl_xor(d1, 32, 64);
        d2s += __shfl_xor(d2s, 16, 64); d2s += __shfl_xor(d2s, 32, 64);
        d3  += __shfl_xor(d3, 16, 64);  d3  += __shfl_xor(d3, 32, 64);
        d4  += __shfl_xor(d4, 16, 64);  d4  += __shfl_xor(d4, 32, 64);
        d5  += __shfl_xor(d5, 16, 64);  d5  += __shfl_xor(d5, 32, 64);
        if (q == 0) {
            unsigned int uid = (unsigned int)id;
            unsigned long long pk;
            float dd;
#define UPD(c, dcv, rm)                                                         \
            dd = a2l[c] + e2 - 2.f * (dcv);                                     \
            pk = ((unsigned long long)fkey(dd) << 32) | uid;                    \
            if (!valid || (c) == lbl) pk = ~0ull;                               \
            rm = (pk < rm) ? pk : rm;
            UPD(0, d0, rmin0) UPD(1, d1, rmin1) UPD(2, d2s, rmin2)
            UPD(3, d3, rmin3) UPD(4, d4, rmin4) UPD(5, d5, rmin5)
#undef UPD
        }
    }
    // min across the 16 g-lanes (q>0 lanes hold ~0ull -> harmless)
#pragma unroll
    for (int m = 1; m <= 8; m <<= 1) {
        unsigned long long o;
#define RED(rm) o = __shfl_xor(rm, m, 64); rm = (o < rm) ? o : rm;
        RED(rmin0) RED(rmin1) RED(rmin2) RED(rmin3) RED(rmin4) RED(rmin5)
#undef RED
    }
    if (lane == 0) {
        if (rmin0 != ~0ull) atomicMin(&lbest[0], rmin0);
        if (rmin1 != ~0ull) atomicMin(&lbest[1], rmin1);
        if (rmin2 != ~0ull) atomicMin(&lbest[2], rmin2);
        if (rmin3 != ~0ull) atomicMin(&lbest[3], rmin3);
        if (rmin4 != ~0ull) atomicMin(&lbest[4], rmin4);
        if (rmin5 != ~0ull) atomicMin(&lbest[5], rmin5);
    }
    __syncthreads();
    if (t < NUM_CLASSES && lbest[t] != ~0ull)
        atomicMin(&gbest[s * NUM_CLASSES + t], lbest[t]);
}

__global__ __launch_bounds__(1024) void k_finalize(const float4* __restrict__ emb4,
                                                   const int* __restrict__ min1,
                                                   const int* __restrict__ min2,
                                                   const int* __restrict__ cntPos,
                                                   const int* __restrict__ cntSbj,
                                                   const unsigned long long* __restrict__ best,
                                                   float* out, int B) {
    __shared__ float vals[NUM_PAIRS];
    __shared__ int vld[NUM_PAIRS];
    int wave = threadIdx.x >> 6;
    int lane = threadIdx.x & 63;
    for (int p = wave; p < NUM_PAIRS; p += (blockDim.x >> 6)) {
        int s = p / NUM_CLASSES;
        int ai = min1[p], pi = min2[p];
        int npos = cntPos[p];
        int nneg = cntSbj[s] - npos;
        unsigned long long bb = best[p];
        int ni = (int)(bb & 0xffffffffu);
        bool ok = (npos >= 2) && (nneg >= 1) && (bb != ~0ull);
        if (ai < 0 || ai >= B) ai = 0;
        if (pi < 0 || pi >= B) pi = 0;
        if (ni < 0 || ni >= B) ni = 0;
        float4 a = emb4[(size_t)ai * 64 + lane];
        float4 pp = emb4[(size_t)pi * 64 + lane];
        float4 nn = emb4[(size_t)ni * 64 + lane];
        float dap = 0.f, dan = 0.f, t;
        t = a.x - pp.x + EPS; dap += t * t;
        t = a.y - pp.y + EPS; dap += t * t;
        t = a.z - pp.z + EPS; dap += t * t;
        t = a.w - pp.w + EPS; dap += t * t;
        t = a.x - nn.x + EPS; dan += t * t;
        t = a.y - nn.y + EPS; dan += t * t;
        t = a.z - nn.z + EPS; dan += t * t;
        t = a.w - nn.w + EPS; dan += t * t;
        dap = wredsum(dap);
        dan = wredsum(dan);
        if (lane == 0) {
            float lv = sqrtf(dap) - sqrtf(dan) + MARGIN;
            vals[p] = ok ? fmaxf(lv, 0.f) : 0.f;
            vld[p] = ok ? 1 : 0;
        }
    }
    __syncthreads();
    if (threadIdx.x == 0) {
        float sum = 0.f;
        int cnt = 0;
        for (int p = 0; p < NUM_PAIRS; ++p) { sum += vals[p]; cnt += vld[p]; }
        out[0] = (cnt > 0) ? (sum / (float)cnt) : 0.f;
    }
}

extern "C" void kernel_launch(void* const* d_in, const int* in_sizes, int n_in,
                              void* d_out, int out_size, void* d_ws, size_t ws_size,
                              hipStream_t stream) {
    const float* emb = (const float*)d_in[0];
    const int* labels = (const int*)d_in[1];
    const int* sbj = (const int*)d_in[2];
    float* out = (float*)d_out;
    const int B = in_sizes[1];           // 131072
    const float4* emb4 = (const float4*)emb;

    char* ws = (char*)d_ws;
    int* min1 = (int*)(ws + 0);
    int* min2 = (int*)(ws + 384);
    int* cntPos = (int*)(ws + 768);
    int* cntSbj = (int*)(ws + 1152);
    unsigned long long* best = (unsigned long long*)(ws + 1216);
    float* a2 = (float*)(ws + 1984);
    int* cursor = (int*)(ws + 2368);
    float4* anchors4 = (float4*)(ws + 2432);
    int* order = (int*)(ws + 395648);

    k_init<<<1, 128, 0, stream>>>(min1, min2, cntPos, cntSbj, best, a2, cursor);

    int blk = 256;
    int grd = (B + blk - 1) / blk;
    k_stats<<<grd, blk, 0, stream>>>(labels, sbj, min1, min2, cntPos, cntSbj, B);
    k_scatter<<<grd, blk, 0, stream>>>(sbj, cntSbj, cursor, order, B);

    k_gather<<<NUM_PAIRS, 64, 0, stream>>>(emb4, min1, anchors4, a2, B);

    k_mine<<<NUM_SUBJECTS * BPS, 1024, 0, stream>>>(emb4, labels, order, cntSbj,
                                                    anchors4, a2, best, B);

    k_finalize<<<1, 1024, 0, stream>>>(emb4, min1, min2, cntPos, cntSbj, best, out, B);
}

// Round 3
// 111.308 us; speedup vs baseline: 3.8910x; 3.8910x over previous
//
#include <hip/hip_runtime.h>
#include <hip/hip_bf16.h>

#define NUM_CLASSES 6
#define NUM_SUBJECTS 16
#define NUM_PAIRS (NUM_CLASSES * NUM_SUBJECTS)   // 96
#define MARGIN 1.0f
#define EPS 1e-6f
#define INF_I 0x7fffffff

// ---------------- ws layout (bytes) ----------------
// [0)      int   min1[96]
// [384)    int   min2[96]
// [768)    int   cntPos[96]
// [1152)   int   cntSbj[16]
// [1216)   u64   best[96]        packed (sortable_f32(d2)<<32)|idx
// [1984)   float a2[96]
// [2368)   int   cursor[16]
// [2432)   f32   anchors[96*256] (float4-aligned)
// [395648) int   order[B]        samples grouped by subject

__device__ __forceinline__ float wredsum(float v) {
#pragma unroll
    for (int m = 32; m >= 1; m >>= 1) v += __shfl_xor(v, m, 64);
    return v;
}

__device__ __forceinline__ unsigned int fkey(float f) {
    unsigned int b = __float_as_uint(f);
    return (b & 0x80000000u) ? ~b : (b | 0x80000000u);
}

__global__ void k_init(int* min1, int* min2, int* cntPos, int* cntSbj,
                       unsigned long long* best, float* a2, int* cursor) {
    int t = threadIdx.x;
    if (t < NUM_PAIRS) {
        min1[t] = INF_I;
        min2[t] = INF_I;
        cntPos[t] = 0;
        best[t] = ~0ull;
        a2[t] = 0.f;
    }
    if (t < NUM_SUBJECTS) cursor[t] = 0;
    if (t >= 64 && t - 64 < NUM_SUBJECTS) cntSbj[t - 64] = 0;
}

// Fused: first-two-positive mining + counts, single pass.
// Lock-free two-min: o = atomicMin(min1, i); atomicMin(min2, max(o, i)).
__global__ void k_stats(const int* __restrict__ labels, const int* __restrict__ sbj,
                        int* min1, int* min2, int* cntPos, int* cntSbj, int B) {
    __shared__ int l1[NUM_PAIRS], l2[NUM_PAIRS], lcp[NUM_PAIRS], lcs[NUM_SUBJECTS];
    for (int t = threadIdx.x; t < NUM_PAIRS; t += blockDim.x) { l1[t] = INF_I; l2[t] = INF_I; lcp[t] = 0; }
    if (threadIdx.x < NUM_SUBJECTS) lcs[threadIdx.x] = 0;
    __syncthreads();
    int i = blockIdx.x * blockDim.x + threadIdx.x;
    if (i < B) {
        int s = sbj[i], c = labels[i];
        int p = s * NUM_CLASSES + c;
        int o = atomicMin(&l1[p], i);
        atomicMin(&l2[p], max(o, i));   // max(INF,i)=INF -> no-op on first insert
        atomicAdd(&lcp[p], 1);
        atomicAdd(&lcs[s], 1);
    }
    __syncthreads();
    for (int t = threadIdx.x; t < NUM_PAIRS; t += blockDim.x) {
        int m1 = l1[t];
        if (m1 != INF_I) {
            int o = atomicMin(&min1[t], m1);
            atomicMin(&min2[t], max(o, m1));
            if (l2[t] != INF_I) atomicMin(&min2[t], l2[t]);
            atomicAdd(&cntPos[t], lcp[t]);
        }
    }
    if (threadIdx.x < NUM_SUBJECTS && lcs[threadIdx.x]) atomicAdd(&cntSbj[threadIdx.x], lcs[threadIdx.x]);
}

// Counting-sort by subject (order within subject is arbitrary; mining is
// order-invariant since the packed min key includes the original index).
__global__ void k_scatter(const int* __restrict__ sbj, const int* __restrict__ cntSbj,
                          int* cursor, int* order, int B) {
    __shared__ int lhist[NUM_SUBJECTS];
    __shared__ int gstart[NUM_SUBJECTS];
    __shared__ int pbase[NUM_SUBJECTS];
    if (threadIdx.x < NUM_SUBJECTS) lhist[threadIdx.x] = 0;
    __syncthreads();
    int i = blockIdx.x * blockDim.x + threadIdx.x;
    int s = 0, lrank = 0;
    bool act = i < B;
    if (act) { s = sbj[i]; lrank = atomicAdd(&lhist[s], 1); }
    __syncthreads();
    if (threadIdx.x == 0) {
        int acc = 0;
#pragma unroll
        for (int t = 0; t < NUM_SUBJECTS; ++t) { pbase[t] = acc; acc += cntSbj[t]; }
    }
    if (threadIdx.x < NUM_SUBJECTS)
        gstart[threadIdx.x] = atomicAdd(&cursor[threadIdx.x], lhist[threadIdx.x]);
    __syncthreads();
    if (act) order[pbase[s] + gstart[s] + lrank] = i;
}

__global__ void k_gather(const float4* __restrict__ emb4, const int* __restrict__ min1,
                         float4* anchors4, float* a2, int B) {
    int p = blockIdx.x;          // 96 blocks
    int lane = threadIdx.x;      // 64 threads
    int idx = min1[p];
    if (idx < 0 || idx >= B) idx = 0;
    float4 v = emb4[(size_t)idx * 64 + lane];
    anchors4[(size_t)p * 64 + lane] = v;
    float t = v.x * v.x + v.y * v.y + v.z * v.z + v.w * v.w;
    t = wredsum(t);
    if (lane == 0) a2[p] = t;
}

#define BPS 64   // blocks per subject; grid = 16*BPS = 1024, 8 waves/block

__global__ __launch_bounds__(512, 2) void k_mine(const float4* __restrict__ emb4,
                                                 const int* __restrict__ labels,
                                                 const int* __restrict__ order,
                                                 const int* __restrict__ cntSbj,
                                                 const float4* __restrict__ anchors4,
                                                 const float* __restrict__ a2,
                                                 unsigned long long* gbest, int B) {
    __shared__ float4 ancLds[NUM_CLASSES][4][17];   // padded: q-stride 17 f4
    __shared__ float a2l[NUM_CLASSES];
    __shared__ unsigned long long lbest[NUM_CLASSES];

    const int s = blockIdx.x & (NUM_SUBJECTS - 1);
    const int j = blockIdx.x >> 4;                  // 0..BPS-1

    int off = 0, cnt = 0;
#pragma unroll
    for (int t = 0; t < NUM_SUBJECTS; ++t) {
        int c = cntSbj[t];
        if (t < s) off += c;
        if (t == s) cnt = c;
    }

    int t = threadIdx.x;
    if (t < NUM_CLASSES * 64) {
        int c = t >> 6, l = t & 63;
        ancLds[c][l >> 4][l & 15] = anchors4[(size_t)(s * NUM_CLASSES + c) * 64 + l];
    }
    if (t < NUM_CLASSES) { a2l[t] = a2[s * NUM_CLASSES + t]; lbest[t] = ~0ull; }
    __syncthreads();
    if (cnt <= 0) return;

    const int lane = threadIdx.x & 63;
    const int g = lane & 15;        // sample-in-chunk
    const int q = lane >> 4;        // dim-quarter
    const int wv = (int)(threadIdx.x >> 6);         // 0..7
    const int waveGlob = j * 8 + wv;                // 0..8*BPS-1
    const int nwv = 8 * BPS;
    const int nchunk = (cnt + 15) >> 4;

    unsigned long long rmin0 = ~0ull, rmin1 = ~0ull, rmin2 = ~0ull,
                       rmin3 = ~0ull, rmin4 = ~0ull, rmin5 = ~0ull;

    for (int ch = waveGlob; ch < nchunk; ch += nwv) {
        int start = ch << 4;
        int rem = cnt - start;
        int gi = start + ((g < rem) ? g : (rem - 1));
        bool valid = g < rem;
        int id = order[off + gi];
        int lbl = labels[id];
        const float4* row = emb4 + (size_t)id * 64 + q * 16;
        float e2 = 0.f, d0 = 0.f, d1 = 0.f, d2s = 0.f, d3 = 0.f, d4 = 0.f, d5 = 0.f;
#pragma unroll 4
        for (int k = 0; k < 16; ++k) {
            float4 v = row[k];
            e2 = fmaf(v.x, v.x, fmaf(v.y, v.y, fmaf(v.z, v.z, fmaf(v.w, v.w, e2))));
            float4 a;
            a = ancLds[0][q][k]; d0  = fmaf(a.x, v.x, fmaf(a.y, v.y, fmaf(a.z, v.z, fmaf(a.w, v.w, d0))));
            a = ancLds[1][q][k]; d1  = fmaf(a.x, v.x, fmaf(a.y, v.y, fmaf(a.z, v.z, fmaf(a.w, v.w, d1))));
            a = ancLds[2][q][k]; d2s = fmaf(a.x, v.x, fmaf(a.y, v.y, fmaf(a.z, v.z, fmaf(a.w, v.w, d2s))));
            a = ancLds[3][q][k]; d3  = fmaf(a.x, v.x, fmaf(a.y, v.y, fmaf(a.z, v.z, fmaf(a.w, v.w, d3))));
            a = ancLds[4][q][k]; d4  = fmaf(a.x, v.x, fmaf(a.y, v.y, fmaf(a.z, v.z, fmaf(a.w, v.w, d4))));
            a = ancLds[5][q][k]; d5  = fmaf(a.x, v.x, fmaf(a.y, v.y, fmaf(a.z, v.z, fmaf(a.w, v.w, d5))));
        }
        // reduce the 4 dim-quarters (partners lane^16, lane^32): 2 shuffles each
        e2  += __shfl_xor(e2, 16, 64);  e2  += __shfl_xor(e2, 32, 64);
        d0  += __shfl_xor(d0, 16, 64);  d0  += __shfl_xor(d0, 32, 64);
        d1  += __shfl_xor(d1, 16, 64);  d1  += __shfl_xor(d1, 32, 64);
        d2s += __shfl_xor(d2s, 16, 64); d2s += __shfl_xor(d2s, 32, 64);
        d3  += __shfl_xor(d3, 16, 64);  d3  += __shfl_xor(d3, 32, 64);
        d4  += __shfl_xor(d4, 16, 64);  d4  += __shfl_xor(d4, 32, 64);
        d5  += __shfl_xor(d5, 16, 64);  d5  += __shfl_xor(d5, 32, 64);
        if (q == 0) {
            unsigned int uid = (unsigned int)id;
            unsigned long long pk;
            float dd;
#define UPD(c, dcv, rm)                                                         \
            dd = a2l[c] + e2 - 2.f * (dcv);                                     \
            pk = ((unsigned long long)fkey(dd) << 32) | uid;                    \
            if (!valid || (c) == lbl) pk = ~0ull;                               \
            rm = (pk < rm) ? pk : rm;
            UPD(0, d0, rmin0) UPD(1, d1, rmin1) UPD(2, d2s, rmin2)
            UPD(3, d3, rmin3) UPD(4, d4, rmin4) UPD(5, d5, rmin5)
#undef UPD
        }
    }
    // min across the 16 g-lanes (q>0 lanes hold ~0ull -> harmless)
#pragma unroll
    for (int m = 1; m <= 8; m <<= 1) {
        unsigned long long o;
#define RED(rm) o = __shfl_xor(rm, m, 64); rm = (o < rm) ? o : rm;
        RED(rmin0) RED(rmin1) RED(rmin2) RED(rmin3) RED(rmin4) RED(rmin5)
#undef RED
    }
    if (lane == 0) {
        if (rmin0 != ~0ull) atomicMin(&lbest[0], rmin0);
        if (rmin1 != ~0ull) atomicMin(&lbest[1], rmin1);
        if (rmin2 != ~0ull) atomicMin(&lbest[2], rmin2);
        if (rmin3 != ~0ull) atomicMin(&lbest[3], rmin3);
        if (rmin4 != ~0ull) atomicMin(&lbest[4], rmin4);
        if (rmin5 != ~0ull) atomicMin(&lbest[5], rmin5);
    }
    __syncthreads();
    if (t < NUM_CLASSES && lbest[t] != ~0ull)
        atomicMin(&gbest[s * NUM_CLASSES + t], lbest[t]);
}

__global__ __launch_bounds__(1024) void k_finalize(const float4* __restrict__ emb4,
                                                   const int* __restrict__ min1,
                                                   const int* __restrict__ min2,
                                                   const int* __restrict__ cntPos,
                                                   const int* __restrict__ cntSbj,
                                                   const unsigned long long* __restrict__ best,
                                                   float* out, int B) {
    __shared__ float vals[NUM_PAIRS];
    __shared__ int vld[NUM_PAIRS];
    int wave = threadIdx.x >> 6;
    int lane = threadIdx.x & 63;
    for (int p = wave; p < NUM_PAIRS; p += (blockDim.x >> 6)) {
        int s = p / NUM_CLASSES;
        int ai = min1[p], pi = min2[p];
        int npos = cntPos[p];
        int nneg = cntSbj[s] - npos;
        unsigned long long bb = best[p];
        int ni = (int)(bb & 0xffffffffu);
        bool ok = (npos >= 2) && (nneg >= 1) && (bb != ~0ull);
        if (ai < 0 || ai >= B) ai = 0;
        if (pi < 0 || pi >= B) pi = 0;
        if (ni < 0 || ni >= B) ni = 0;
        float4 a = emb4[(size_t)ai * 64 + lane];
        float4 pp = emb4[(size_t)pi * 64 + lane];
        float4 nn = emb4[(size_t)ni * 64 + lane];
        float dap = 0.f, dan = 0.f, t;
        t = a.x - pp.x + EPS; dap += t * t;
        t = a.y - pp.y + EPS; dap += t * t;
        t = a.z - pp.z + EPS; dap += t * t;
        t = a.w - pp.w + EPS; dap += t * t;
        t = a.x - nn.x + EPS; dan += t * t;
        t = a.y - nn.y + EPS; dan += t * t;
        t = a.z - nn.z + EPS; dan += t * t;
        t = a.w - nn.w + EPS; dan += t * t;
        dap = wredsum(dap);
        dan = wredsum(dan);
        if (lane == 0) {
            float lv = sqrtf(dap) - sqrtf(dan) + MARGIN;
            vals[p] = ok ? fmaxf(lv, 0.f) : 0.f;
            vld[p] = ok ? 1 : 0;
        }
    }
    __syncthreads();
    if (threadIdx.x == 0) {
        float sum = 0.f;
        int cnt = 0;
        for (int p = 0; p < NUM_PAIRS; ++p) { sum += vals[p]; cnt += vld[p]; }
        out[0] = (cnt > 0) ? (sum / (float)cnt) : 0.f;
    }
}

extern "C" void kernel_launch(void* const* d_in, const int* in_sizes, int n_in,
                              void* d_out, int out_size, void* d_ws, size_t ws_size,
                              hipStream_t stream) {
    const float* emb = (const float*)d_in[0];
    const int* labels = (const int*)d_in[1];
    const int* sbj = (const int*)d_in[2];
    float* out = (float*)d_out;
    const int B = in_sizes[1];           // 131072
    const float4* emb4 = (const float4*)emb;

    char* ws = (char*)d_ws;
    int* min1 = (int*)(ws + 0);
    int* min2 = (int*)(ws + 384);
    int* cntPos = (int*)(ws + 768);
    int* cntSbj = (int*)(ws + 1152);
    unsigned long long* best = (unsigned long long*)(ws + 1216);
    float* a2 = (float*)(ws + 1984);
    int* cursor = (int*)(ws + 2368);
    float4* anchors4 = (float4*)(ws + 2432);
    int* order = (int*)(ws + 395648);

    k_init<<<1, 128, 0, stream>>>(min1, min2, cntPos, cntSbj, best, a2, cursor);

    int blk = 256;
    int grd = (B + blk - 1) / blk;
    k_stats<<<grd, blk, 0, stream>>>(labels, sbj, min1, min2, cntPos, cntSbj, B);
    k_scatter<<<grd, blk, 0, stream>>>(sbj, cntSbj, cursor, order, B);

    k_gather<<<NUM_PAIRS, 64, 0, stream>>>(emb4, min1, anchors4, a2, B);

    k_mine<<<NUM_SUBJECTS * BPS, 512, 0, stream>>>(emb4, labels, order, cntSbj,
                                                   anchors4, a2, best, B);

    k_finalize<<<1, 1024, 0, stream>>>(emb4, min1, min2, cntPos, cntSbj, best, out, B);
}

// Round 4
// 80.404 us; speedup vs baseline: 5.3865x; 1.3844x over previous
//
#include <hip/hip_runtime.h>

#define NUM_CLASSES 6
#define NUM_SUBJECTS 16
#define NUM_PAIRS (NUM_CLASSES * NUM_SUBJECTS)   // 96
#define MARGIN 1.0f
#define EPS 1e-6f
#define INF_I 0x7fffffff

// ---------------- ws layout (bytes) ----------------
// [0)      int   min1[96]
// [384)    int   min2[96]
// [768)    int   cntPos[96]
// [1152)   int   cntSbj[16]
// [1216)   u64   best[96]        packed (sortable_f32(d2)<<32)|idx
// [1984)   float a2[96]
// [2432)   f32   anchors[96*256] (float4-aligned)

__device__ __forceinline__ float wredsum(float v) {
#pragma unroll
    for (int m = 32; m >= 1; m >>= 1) v += __shfl_xor(v, m, 64);
    return v;
}

__device__ __forceinline__ unsigned int fkey(float f) {
    unsigned int b = __float_as_uint(f);
    return (b & 0x80000000u) ? ~b : (b | 0x80000000u);
}

// f32 -> bf16 bits, RTNE (inputs are normal randoms; NaN not expected)
__device__ __forceinline__ unsigned short f2bf(float f) {
    unsigned int u = __float_as_uint(f);
    unsigned int r = u + 0x7fffu + ((u >> 16) & 1u);
    return (unsigned short)(r >> 16);
}

__global__ void k_init(int* min1, int* min2, int* cntPos, int* cntSbj,
                       unsigned long long* best, float* a2) {
    int t = threadIdx.x;
    if (t < NUM_PAIRS) {
        min1[t] = INF_I;
        min2[t] = INF_I;
        cntPos[t] = 0;
        best[t] = ~0ull;
        a2[t] = 0.f;
    }
    if (t < NUM_SUBJECTS) cntSbj[t] = 0;
}

// Fused: first-two-positive mining + counts, single pass.
// Lock-free two-min: o = atomicMin(min1, i); atomicMin(min2, max(o, i)).
__global__ void k_stats(const int* __restrict__ labels, const int* __restrict__ sbj,
                        int* min1, int* min2, int* cntPos, int* cntSbj, int B) {
    __shared__ int l1[NUM_PAIRS], l2[NUM_PAIRS], lcp[NUM_PAIRS], lcs[NUM_SUBJECTS];
    for (int t = threadIdx.x; t < NUM_PAIRS; t += blockDim.x) { l1[t] = INF_I; l2[t] = INF_I; lcp[t] = 0; }
    if (threadIdx.x < NUM_SUBJECTS) lcs[threadIdx.x] = 0;
    __syncthreads();
    int i = blockIdx.x * blockDim.x + threadIdx.x;
    if (i < B) {
        int s = sbj[i], c = labels[i];
        int p = s * NUM_CLASSES + c;
        int o = atomicMin(&l1[p], i);
        atomicMin(&l2[p], max(o, i));   // max(INF,i)=INF -> no-op on first insert
        atomicAdd(&lcp[p], 1);
        atomicAdd(&lcs[s], 1);
    }
    __syncthreads();
    for (int t = threadIdx.x; t < NUM_PAIRS; t += blockDim.x) {
        int m1 = l1[t];
        if (m1 != INF_I) {
            int o = atomicMin(&min1[t], m1);
            atomicMin(&min2[t], max(o, m1));
            if (l2[t] != INF_I) atomicMin(&min2[t], l2[t]);
            atomicAdd(&cntPos[t], lcp[t]);
        }
    }
    if (threadIdx.x < NUM_SUBJECTS && lcs[threadIdx.x]) atomicAdd(&cntSbj[threadIdx.x], lcs[threadIdx.x]);
}

__global__ void k_gather(const float4* __restrict__ emb4, const int* __restrict__ min1,
                         float4* anchors4, float* a2, int B) {
    int p = blockIdx.x;          // 96 blocks
    int lane = threadIdx.x;      // 64 threads
    int idx = min1[p];
    if (idx < 0 || idx >= B) idx = 0;
    float4 v = emb4[(size_t)idx * 64 + lane];
    anchors4[(size_t)p * 64 + lane] = v;
    float t = v.x * v.x + v.y * v.y + v.z * v.z + v.w * v.w;
    t = wredsum(t);
    if (lane == 0) a2[p] = t;
}

// Natural-order streaming mine: 1 lane = 1 sample, wave reads a contiguous
// 64 KB block of emb. Anchors as bf16 in LDS, subject stride 3080 B
// (= 385 u64) so the 16 subject base addresses land on distinct bank pairs
// (385*8/4 mod 32 = 2 -> subjects at banks 0,2,...,30), same-subject lanes
// broadcast. 5 LDS u64 atomicMin per sample; filtered global flush per block.
__global__ __launch_bounds__(512, 2) void k_mine(const float4* __restrict__ emb4,
                                                 const int* __restrict__ labels,
                                                 const int* __restrict__ sbj,
                                                 const float4* __restrict__ anchors4,
                                                 const float* __restrict__ a2,
                                                 unsigned long long* gbest, int B) {
    __shared__ unsigned long long ancB64[NUM_SUBJECTS * 385];   // 49280 B
    __shared__ float a2l[NUM_PAIRS];
    __shared__ unsigned long long lbest[NUM_PAIRS];

    // stage anchors f32 -> bf16x4 packed u64
    for (int u = threadIdx.x; u < NUM_PAIRS * 64; u += blockDim.x) {
        int row = u >> 6;            // s*6+c
        int grp = u & 63;            // float4 group (4 dims)
        float4 v = anchors4[u];
        unsigned int lo = (unsigned int)f2bf(v.x) | ((unsigned int)f2bf(v.y) << 16);
        unsigned int hi = (unsigned int)f2bf(v.z) | ((unsigned int)f2bf(v.w) << 16);
        int s = row / NUM_CLASSES, c = row - s * NUM_CLASSES;
        ancB64[s * 385 + c * 64 + grp] = (unsigned long long)lo | ((unsigned long long)hi << 32);
    }
    for (int t = threadIdx.x; t < NUM_PAIRS; t += blockDim.x) {
        a2l[t] = a2[t];
        lbest[t] = ~0ull;
    }
    __syncthreads();

    const int lane = threadIdx.x & 63;
    const int wv = (int)(threadIdx.x >> 6);
    const int wavesPerBlk = (int)(blockDim.x >> 6);
    const int waveGlob = (int)blockIdx.x * wavesPerBlk + wv;
    const int nwv = (int)gridDim.x * wavesPerBlk;
    const int nchunk = (B + 63) >> 6;

    for (int ch = waveGlob; ch < nchunk; ch += nwv) {
        int i = ch * 64 + lane;
        bool valid = i < B;
        int ic = valid ? i : (B - 1);
        int s = sbj[ic];
        int lbl = labels[ic];
        const float4* row = emb4 + (size_t)ic * 64;
        const unsigned long long* anc = ancB64 + s * 385;
        float e2 = 0.f, d0 = 0.f, d1 = 0.f, d2v = 0.f, d3 = 0.f, d4 = 0.f, d5 = 0.f;
#pragma unroll 4
        for (int k = 0; k < 64; ++k) {
            float4 v = row[k];
            e2 = fmaf(v.x, v.x, fmaf(v.y, v.y, fmaf(v.z, v.z, fmaf(v.w, v.w, e2))));
            unsigned long long A;
            unsigned int lo, hi;
            float a0, a1, a2f, a3;
#define DOT(C, ACC)                                                              \
            A = anc[(C) * 64 + k];                                               \
            lo = (unsigned int)A; hi = (unsigned int)(A >> 32);                  \
            a0 = __uint_as_float(lo << 16);                                      \
            a1 = __uint_as_float(lo & 0xffff0000u);                              \
            a2f = __uint_as_float(hi << 16);                                     \
            a3 = __uint_as_float(hi & 0xffff0000u);                              \
            ACC = fmaf(a0, v.x, fmaf(a1, v.y, fmaf(a2f, v.z, fmaf(a3, v.w, ACC))));
            DOT(0, d0) DOT(1, d1) DOT(2, d2v) DOT(3, d3) DOT(4, d4) DOT(5, d5)
#undef DOT
        }
        if (valid) {
            int pb = s * NUM_CLASSES;
            float dc[NUM_CLASSES] = {d0, d1, d2v, d3, d4, d5};
#pragma unroll
            for (int c = 0; c < NUM_CLASSES; ++c) {
                if (c != lbl) {
                    float dd = a2l[pb + c] + e2 - 2.f * dc[c];
                    unsigned long long pk =
                        ((unsigned long long)fkey(dd) << 32) | (unsigned int)i;
                    atomicMin(&lbest[pb + c], pk);
                }
            }
        }
    }
    __syncthreads();
    for (int t = threadIdx.x; t < NUM_PAIRS; t += blockDim.x) {
        unsigned long long v = lbest[t];
        if (v != ~0ull) {
            unsigned long long cur = gbest[t];   // racy read; monotone decreasing -> safe filter
            if (v < cur) atomicMin(&gbest[t], v);
        }
    }
}

__global__ __launch_bounds__(1024) void k_finalize(const float4* __restrict__ emb4,
                                                   const int* __restrict__ min1,
                                                   const int* __restrict__ min2,
                                                   const int* __restrict__ cntPos,
                                                   const int* __restrict__ cntSbj,
                                                   const unsigned long long* __restrict__ best,
                                                   float* out, int B) {
    __shared__ float vals[NUM_PAIRS];
    __shared__ int vld[NUM_PAIRS];
    int wave = threadIdx.x >> 6;
    int lane = threadIdx.x & 63;
    for (int p = wave; p < NUM_PAIRS; p += (blockDim.x >> 6)) {
        int s = p / NUM_CLASSES;
        int ai = min1[p], pi = min2[p];
        int npos = cntPos[p];
        int nneg = cntSbj[s] - npos;
        unsigned long long bb = best[p];
        int ni = (int)(bb & 0xffffffffu);
        bool ok = (npos >= 2) && (nneg >= 1) && (bb != ~0ull);
        if (ai < 0 || ai >= B) ai = 0;
        if (pi < 0 || pi >= B) pi = 0;
        if (ni < 0 || ni >= B) ni = 0;
        float4 a = emb4[(size_t)ai * 64 + lane];
        float4 pp = emb4[(size_t)pi * 64 + lane];
        float4 nn = emb4[(size_t)ni * 64 + lane];
        float dap = 0.f, dan = 0.f, t;
        t = a.x - pp.x + EPS; dap += t * t;
        t = a.y - pp.y + EPS; dap += t * t;
        t = a.z - pp.z + EPS; dap += t * t;
        t = a.w - pp.w + EPS; dap += t * t;
        t = a.x - nn.x + EPS; dan += t * t;
        t = a.y - nn.y + EPS; dan += t * t;
        t = a.z - nn.z + EPS; dan += t * t;
        t = a.w - nn.w + EPS; dan += t * t;
        dap = wredsum(dap);
        dan = wredsum(dan);
        if (lane == 0) {
            float lv = sqrtf(dap) - sqrtf(dan) + MARGIN;
            vals[p] = ok ? fmaxf(lv, 0.f) : 0.f;
            vld[p] = ok ? 1 : 0;
        }
    }
    __syncthreads();
    if (threadIdx.x == 0) {
        float sum = 0.f;
        int cnt = 0;
        for (int p = 0; p < NUM_PAIRS; ++p) { sum += vals[p]; cnt += vld[p]; }
        out[0] = (cnt > 0) ? (sum / (float)cnt) : 0.f;
    }
}

extern "C" void kernel_launch(void* const* d_in, const int* in_sizes, int n_in,
                              void* d_out, int out_size, void* d_ws, size_t ws_size,
                              hipStream_t stream) {
    const float* emb = (const float*)d_in[0];
    const int* labels = (const int*)d_in[1];
    const int* sbj = (const int*)d_in[2];
    float* out = (float*)d_out;
    const int B = in_sizes[1];           // 131072
    const float4* emb4 = (const float4*)emb;

    char* ws = (char*)d_ws;
    int* min1 = (int*)(ws + 0);
    int* min2 = (int*)(ws + 384);
    int* cntPos = (int*)(ws + 768);
    int* cntSbj = (int*)(ws + 1152);
    unsigned long long* best = (unsigned long long*)(ws + 1216);
    float* a2 = (float*)(ws + 1984);
    float4* anchors4 = (float4*)(ws + 2432);

    k_init<<<1, 128, 0, stream>>>(min1, min2, cntPos, cntSbj, best, a2);

    int blk = 256;
    int grd = (B + blk - 1) / blk;
    k_stats<<<grd, blk, 0, stream>>>(labels, sbj, min1, min2, cntPos, cntSbj, B);

    k_gather<<<NUM_PAIRS, 64, 0, stream>>>(emb4, min1, anchors4, a2, B);

    int nchunk = (B + 63) >> 6;
    int mblocks = (nchunk + 7) / 8;      // 8 waves/block, 1 chunk/wave
    if (mblocks > 2048) mblocks = 2048;
    k_mine<<<mblocks, 512, 0, stream>>>(emb4, labels, sbj, anchors4, a2, best, B);

    k_finalize<<<1, 1024, 0, stream>>>(emb4, min1, min2, cntPos, cntSbj, best, out, B);
}